// Round 12
// baseline (120.642 us; speedup 1.0000x reference)
//
#include <hip/hip_runtime.h>
#include <hip/hip_bf16.h>

// Problem constants
#define D_DIM 512
#define K_DIM 512
#define B_C   64

// R5-validated tile: 128x128, 4 waves (2x2), BK=64, LDS dbuf 64 KiB.
// NEW: persistent-pair grid — 512 blocks (2/CU exactly); block (b,ct,h)
// processes row-tiles rt = h, h+2, ... (stride-2), halving W re-reads.
#define BM 128
#define BN 128
#define BK 64
#define KSTEPS 8             // D_DIM / BK
#define ROWT 8               // LMAX / BM
#define COLT 4               // K_DIM / BN
#define HALVES 2
#define NWG  (B_C * COLT * HALVES)   // 512, divisible by 8 XCDs

typedef __attribute__((ext_vector_type(8))) short bf16x8;
typedef __attribute__((ext_vector_type(4))) float f32x4;

__device__ __forceinline__ short f2bf(float f) {
    union { __hip_bfloat16 h; short s; } u;
    u.h = __float2bfloat16(f);
    return u.s;
}

// R3/R5-validated zero-conflict swizzle for 128B rows (8 x 16B slots):
// slot' = slot ^ ((r&7) ^ ((r>>2)&7))
__device__ __forceinline__ int fS(int r) { return (r & 7) ^ ((r >> 2) & 7); }
__device__ __forceinline__ char* lds_addr(short* base, int row, int kbyte) {
    return (char*)base + row * 128 + (kbyte ^ (fS(row) << 4));
}

__global__ __launch_bounds__(256, 2) void jbmm_kernel(
    const int* __restrict__ offsets,   // B+1
    const int* __restrict__ index,     // B
    const float* __restrict__ jagged,  // T x D
    const float* __restrict__ weight,  // NW x D x K
    const float* __restrict__ bias,    // NW x K
    float* __restrict__ out)           // T x K
{
    __shared__ short As[2][BM * BK];   // 16 KB each
    __shared__ short Bs[2][BN * BK];   // 16 KB each

    // XCD chunk swizzle (512 % 8 == 0 -> bijective); h-adjacent logical ids
    // land on the same XCD so both halves of a (b,ct) share W in one L2.
    const int bidRaw = blockIdx.x;
    const int bid = (bidRaw & 7) * (NWG / 8) + (bidRaw >> 3);

    const int h    = bid & 1;
    const int pair = bid >> 1;
    const int ct   = pair & 3;
    const int b    = pair >> 2;

    const int start = offsets[b];
    const int end   = offsets[b + 1];
    int rt = h;
    int m0 = start + rt * BM;
    if (m0 >= end) return;
    int rows = (end - m0) < BM ? (end - m0) : BM;

    const int idxw = index[b];
    const float* W = weight + (size_t)idxw * D_DIM * K_DIM;
    const int n0 = ct * BN;

    const int tid  = threadIdx.x;
    const int lane = tid & 63;
    const int wid  = tid >> 6;
    const int wr   = wid >> 1;   // wave row (2x2)
    const int wc   = wid & 1;    // wave col
    const int lr   = lane & 15;
    const int lg   = lane >> 4;

    // staging maps (R5)
    const int arow  = tid >> 3;  // 0..31 (+32*i): A row
    const int acol8 = tid & 7;   // 8 consecutive f32 at k = acol8*8
    const int n4    = tid & 31;  // B n-quad (rows 4*n4..+3)
    const int dq8   = tid >> 5;  // B k-octet 0..7

    float bias_v[4];
#pragma unroll
    for (int ni = 0; ni < 4; ++ni)
        bias_v[ni] = bias[(size_t)idxw * K_DIM + n0 + wc * 64 + ni * 16 + lr];

    f32x4 acc[4][4];
#pragma unroll
    for (int mi = 0; mi < 4; ++mi)
#pragma unroll
        for (int ni = 0; ni < 4; ++ni)
            acc[mi][ni] = (f32x4){0.f, 0.f, 0.f, 0.f};

    f32x4 aR[8];
    f32x4 bR[8];

#define LOADA(k0_, M0_, ROWS_)                                              \
    {                                                                       \
        _Pragma("unroll")                                                   \
        for (int i = 0; i < 4; ++i) {                                       \
            const int r = arow + 32 * i;                                    \
            f32x4 v0 = (f32x4){0.f,0.f,0.f,0.f};                            \
            f32x4 v1 = (f32x4){0.f,0.f,0.f,0.f};                            \
            if (r < (ROWS_)) {                                              \
                const float* p = &jagged[(size_t)((M0_) + r) * D_DIM + (k0_) + acol8 * 8]; \
                v0 = *reinterpret_cast<const f32x4*>(p);                    \
                v1 = *reinterpret_cast<const f32x4*>(p + 4);                \
            }                                                               \
            aR[2 * i] = v0; aR[2 * i + 1] = v1;                             \
        }                                                                   \
    }

#define LOADB(k0_)                                                          \
    {                                                                       \
        _Pragma("unroll")                                                   \
        for (int j = 0; j < 8; ++j)                                         \
            bR[j] = *reinterpret_cast<const f32x4*>(                        \
                &W[(size_t)((k0_) + dq8 * 8 + j) * K_DIM + n0 + n4 * 4]);   \
    }

#define CVTSTORE(c_)                                                        \
    {                                                                       \
        _Pragma("unroll")                                                   \
        for (int i = 0; i < 4; ++i) {                                       \
            const int r = arow + 32 * i;                                    \
            bf16x8 w8;                                                      \
            w8[0] = f2bf(aR[2*i][0]); w8[1] = f2bf(aR[2*i][1]);             \
            w8[2] = f2bf(aR[2*i][2]); w8[3] = f2bf(aR[2*i][3]);             \
            w8[4] = f2bf(aR[2*i+1][0]); w8[5] = f2bf(aR[2*i+1][1]);         \
            w8[6] = f2bf(aR[2*i+1][2]); w8[7] = f2bf(aR[2*i+1][3]);         \
            *reinterpret_cast<bf16x8*>(lds_addr(&As[c_][0], r, acol8 * 16)) = w8; \
        }                                                                   \
        _Pragma("unroll")                                                   \
        for (int np = 0; np < 4; ++np) {                                    \
            const int row = n4 * 4 + np;                                    \
            bf16x8 w8;                                                      \
            w8[0] = f2bf(bR[0][np]); w8[1] = f2bf(bR[1][np]);               \
            w8[2] = f2bf(bR[2][np]); w8[3] = f2bf(bR[3][np]);               \
            w8[4] = f2bf(bR[4][np]); w8[5] = f2bf(bR[5][np]);               \
            w8[6] = f2bf(bR[6][np]); w8[7] = f2bf(bR[7][np]);               \
            *reinterpret_cast<bf16x8*>(lds_addr(&Bs[c_][0], row, dq8 * 16)) = w8; \
        }                                                                   \
    }

#define COMPUTE(c_)                                                         \
    {                                                                       \
        __builtin_amdgcn_s_setprio(1);                                      \
        _Pragma("unroll")                                                   \
        for (int kh = 0; kh < 2; ++kh) {                                    \
            bf16x8 af[4], bfr[4];                                           \
            _Pragma("unroll")                                               \
            for (int mi = 0; mi < 4; ++mi)                                  \
                af[mi] = *reinterpret_cast<bf16x8*>(                        \
                    lds_addr(&As[c_][0], wr * 64 + mi * 16 + lr, kh * 64 + lg * 16)); \
            _Pragma("unroll")                                               \
            for (int ni = 0; ni < 4; ++ni)                                  \
                bfr[ni] = *reinterpret_cast<bf16x8*>(                       \
                    lds_addr(&Bs[c_][0], wc * 64 + ni * 16 + lr, kh * 64 + lg * 16)); \
            _Pragma("unroll")                                               \
            for (int mi = 0; mi < 4; ++mi)                                  \
                _Pragma("unroll")                                           \
                for (int ni = 0; ni < 4; ++ni)                              \
                    acc[mi][ni] = __builtin_amdgcn_mfma_f32_16x16x32_bf16(  \
                        af[mi], bfr[ni], acc[mi][ni], 0, 0, 0);             \
        }                                                                   \
        __builtin_amdgcn_s_setprio(0);                                      \
    }

// Raw barrier: only LDS ops must drain; global loads stay in flight.
#define BARRIER_LDS()                                                       \
    {                                                                       \
        asm volatile("s_waitcnt lgkmcnt(0)" ::: "memory");                  \
        __builtin_amdgcn_s_barrier();                                       \
        asm volatile("" ::: "memory");                                      \
    }

    // ---- prologue of first tile ----
    LOADA(0, m0, rows); LOADB(0);
    CVTSTORE(0);
    BARRIER_LDS();

    // ---- persistent loop over this block's row-tiles (rt = h, h+2, ...) ----
    while (true) {
#pragma unroll
        for (int t = 0; t < KSTEPS; ++t) {
            if (t + 1 < KSTEPS) {
                const int kn = (t + 1) * BK;
                LOADA(kn, m0, rows); LOADB(kn);   // in flight across COMPUTE
            }
            COMPUTE(t & 1);
            if (t + 1 < KSTEPS) {
                CVTSTORE((t + 1) & 1);
                BARRIER_LDS();
            }
        }

        // issue next tile's step-0 loads BEFORE the epilogue stores,
        // so the inter-tile seam is covered by the store phase.
        const int rtn  = rt + HALVES;
        const int m0n  = start + rtn * BM;
        const bool more = (m0n < end);
        const int rowsn = more ? ((end - m0n) < BM ? (end - m0n) : BM) : 0;
        if (more) { LOADA(0, m0n, rowsn); LOADB(0); }

        // ---- epilogue: C/D layout col=lane&15, row=(lane>>4)*4+r ----
#pragma unroll
        for (int mi = 0; mi < 4; ++mi) {
            const int rloc = wr * 64 + mi * 16 + lg * 4;
#pragma unroll
            for (int r = 0; r < 4; ++r) {
                const int rr = rloc + r;
                if (rr < rows) {
#pragma unroll
                    for (int ni = 0; ni < 4; ++ni) {
                        out[(size_t)(m0 + rr) * K_DIM + n0 + wc * 64 + ni * 16 + lr] =
                            acc[mi][ni][r] + bias_v[ni];
                    }
                }
            }
        }
        if (!more) break;

#pragma unroll
        for (int mi = 0; mi < 4; ++mi)
#pragma unroll
            for (int ni = 0; ni < 4; ++ni)
                acc[mi][ni] = (f32x4){0.f, 0.f, 0.f, 0.f};
        m0 = m0n; rows = rowsn; rt = rtn;

        // buf0 was last read at t=6 (behind a barrier) -> safe to refill.
        CVTSTORE(0);
        BARRIER_LDS();
    }
}

extern "C" void kernel_launch(void* const* d_in, const int* in_sizes, int n_in,
                              void* d_out, int out_size, void* d_ws, size_t ws_size,
                              hipStream_t stream) {
    const int*   offsets = (const int*)d_in[1];
    const int*   index   = (const int*)d_in[2];
    const float* jagged  = (const float*)d_in[3];
    const float* weight  = (const float*)d_in[4];
    const float* bias    = (const float*)d_in[5];
    float*       out     = (float*)d_out;

    dim3 grid(NWG);    // 512 blocks = exactly 2 per CU
    dim3 block(256);
    hipLaunchKernelGGL(jbmm_kernel, grid, block, 0, stream,
                       offsets, index, jagged, weight, bias, out);
}

// Round 13
// 117.890 us; speedup vs baseline: 1.0233x; 1.0233x over previous
//
#include <hip/hip_runtime.h>
#include <hip/hip_bf16.h>

// Problem constants
#define D_DIM 512
#define K_DIM 512
#define B_C   64

// 256x256 tile (AI=64), 8 waves (2 wave-rows x 4 wave-cols), BK=64,
// LDS dbuf 128 KiB, FULL 256-VGPR budget (launch_bounds(512,1)) -> no spill.
#define BM 256
#define BN 256
#define BK 64
#define KSTEPS 8             // D_DIM / BK
#define ROWT 4               // LMAX / BM
#define COLT 2               // K_DIM / BN
#define NWG  (B_C * ROWT * COLT)   // 512, divisible by 8 XCDs

typedef __attribute__((ext_vector_type(8))) short bf16x8;
typedef __attribute__((ext_vector_type(4))) float f32x4;

__device__ __forceinline__ short f2bf(float f) {
    union { __hip_bfloat16 h; short s; } u;
    u.h = __float2bfloat16(f);
    return u.s;
}

// R3/R5-validated zero-conflict swizzle for 128B rows (8 x 16B slots):
// slot' = slot ^ ((r&7) ^ ((r>>2)&7))
__device__ __forceinline__ int fS(int r) { return (r & 7) ^ ((r >> 2) & 7); }

__global__ __launch_bounds__(512, 1) void jbmm_kernel(
    const int* __restrict__ offsets,   // B+1
    const int* __restrict__ index,     // B
    const float* __restrict__ jagged,  // T x D
    const float* __restrict__ weight,  // NW x D x K
    const float* __restrict__ bias,    // NW x K
    float* __restrict__ out)           // T x K
{
    __shared__ short As[2][BM * BK];   // 32 KB each
    __shared__ short Bs[2][BN * BK];   // 32 KB each

    // XCD chunk swizzle (512 % 8 == 0 -> bijective)
    const int bidRaw = blockIdx.x;
    const int bid = (bidRaw & 7) * (NWG / 8) + (bidRaw >> 3);

    const int b   = bid / (ROWT * COLT);
    const int rt  = (bid / COLT) % ROWT;
    const int ct  = bid % COLT;

    const int start = offsets[b];
    const int end   = offsets[b + 1];
    const int m0    = start + rt * BM;
    if (m0 >= end) return;
    const int rows = (end - m0) < BM ? (end - m0) : BM;

    const int idxw = index[b];
    const float* W = weight + (size_t)idxw * D_DIM * K_DIM;
    const int n0 = ct * BN;

    const int tid  = threadIdx.x;
    const int lane = tid & 63;
    const int wid  = tid >> 6;   // 0..7
    const int wr   = wid >> 2;   // 0..1: rows wr*128..+127
    const int wc   = wid & 3;    // 0..3: cols wc*64..+63
    const int lr   = lane & 15;
    const int lg   = lane >> 4;

    // staging maps (512 threads)
    const int arow  = tid >> 1;  // 0..255: A row
    const int ahalf = tid & 1;   // 0..1: 32 consecutive f32
    const int nq    = tid & 63;  // 0..63: B n-quad (rows 4*nq..+3)
    const int ko8   = tid >> 6;  // 0..7: k-octet

    float bias_v[4];
#pragma unroll
    for (int ni = 0; ni < 4; ++ni)
        bias_v[ni] = bias[(size_t)idxw * K_DIM + n0 + wc * 64 + ni * 16 + lr];

    f32x4 acc[8][4];             // 128 VGPR
#pragma unroll
    for (int mi = 0; mi < 8; ++mi)
#pragma unroll
        for (int ni = 0; ni < 4; ++ni)
            acc[mi][ni] = (f32x4){0.f, 0.f, 0.f, 0.f};

    f32x4 aR[8];                 // A: one row, 32 consecutive f32
    f32x4 bR[8];                 // B: 8 k-rows x 4 n

#define LOADA(k0_)                                                          \
    {                                                                       \
        if (arow < rows) {                                                  \
            const float* p = &jagged[(size_t)(m0 + arow) * D_DIM + (k0_) + ahalf * 32]; \
            _Pragma("unroll")                                               \
            for (int j = 0; j < 8; ++j)                                     \
                aR[j] = *reinterpret_cast<const f32x4*>(p + 4 * j);         \
        } else {                                                            \
            _Pragma("unroll")                                               \
            for (int j = 0; j < 8; ++j)                                     \
                aR[j] = (f32x4){0.f, 0.f, 0.f, 0.f};                        \
        }                                                                   \
    }

#define LOADB(k0_)                                                          \
    {                                                                       \
        _Pragma("unroll")                                                   \
        for (int j = 0; j < 8; ++j)                                         \
            bR[j] = *reinterpret_cast<const f32x4*>(                        \
                &W[(size_t)((k0_) + ko8 * 8 + j) * K_DIM + n0 + nq * 4]);   \
    }

#define CVTSTORE(c_)                                                        \
    {                                                                       \
        _Pragma("unroll")                                                   \
        for (int q = 0; q < 4; ++q) {                                       \
            bf16x8 w8;                                                      \
            w8[0] = f2bf(aR[2*q][0]);   w8[1] = f2bf(aR[2*q][1]);           \
            w8[2] = f2bf(aR[2*q][2]);   w8[3] = f2bf(aR[2*q][3]);           \
            w8[4] = f2bf(aR[2*q+1][0]); w8[5] = f2bf(aR[2*q+1][1]);         \
            w8[6] = f2bf(aR[2*q+1][2]); w8[7] = f2bf(aR[2*q+1][3]);         \
            const int sl = (ahalf * 4 + q) ^ fS(arow);                      \
            *reinterpret_cast<bf16x8*>(                                     \
                (char*)&As[c_][0] + arow * 128 + (sl << 4)) = w8;           \
        }                                                                   \
        _Pragma("unroll")                                                   \
        for (int np = 0; np < 4; ++np) {                                    \
            const int row = nq * 4 + np;                                    \
            bf16x8 w8;                                                      \
            w8[0] = f2bf(bR[0][np]); w8[1] = f2bf(bR[1][np]);               \
            w8[2] = f2bf(bR[2][np]); w8[3] = f2bf(bR[3][np]);               \
            w8[4] = f2bf(bR[4][np]); w8[5] = f2bf(bR[5][np]);               \
            w8[6] = f2bf(bR[6][np]); w8[7] = f2bf(bR[7][np]);               \
            const int sl = ko8 ^ fS(row);                                   \
            *reinterpret_cast<bf16x8*>(                                     \
                (char*)&Bs[c_][0] + row * 128 + (sl << 4)) = w8;            \
        }                                                                   \
    }

#define COMPUTE(c_)                                                         \
    {                                                                       \
        __builtin_amdgcn_s_setprio(1);                                      \
        _Pragma("unroll")                                                   \
        for (int kh = 0; kh < 2; ++kh) {                                    \
            bf16x8 bfr[4];                                                  \
            _Pragma("unroll")                                               \
            for (int ni = 0; ni < 4; ++ni) {                                \
                const int row = wc * 64 + ni * 16 + lr;                     \
                bfr[ni] = *reinterpret_cast<bf16x8*>(                       \
                    (char*)&Bs[c_][0] + row * 128 + (((kh * 4 + lg) ^ fS(row)) << 4)); \
            }                                                               \
            _Pragma("unroll")                                               \
            for (int mi = 0; mi < 8; ++mi) {                                \
                const int row = wr * 128 + mi * 16 + lr;                    \
                bf16x8 af = *reinterpret_cast<bf16x8*>(                     \
                    (char*)&As[c_][0] + row * 128 + (((kh * 4 + lg) ^ fS(row)) << 4)); \
                _Pragma("unroll")                                           \
                for (int ni = 0; ni < 4; ++ni)                              \
                    acc[mi][ni] = __builtin_amdgcn_mfma_f32_16x16x32_bf16(  \
                        af, bfr[ni], acc[mi][ni], 0, 0, 0);                 \
            }                                                               \
        }                                                                   \
        __builtin_amdgcn_s_setprio(0);                                      \
    }

// Raw barrier: only LDS ops must drain; global loads stay in flight.
#define BARRIER_LDS()                                                       \
    {                                                                       \
        asm volatile("s_waitcnt lgkmcnt(0)" ::: "memory");                  \
        __builtin_amdgcn_s_barrier();                                       \
        asm volatile("" ::: "memory");                                      \
    }

    // ---- prologue ----
    LOADA(0); LOADB(0);
    CVTSTORE(0);
    BARRIER_LDS();

    // ---- main loop (R5 schedule): loads at top stay in flight across COMPUTE ----
#pragma unroll
    for (int t = 0; t < KSTEPS; ++t) {
        if (t + 1 < KSTEPS) {
            const int kn = (t + 1) * BK;
            LOADA(kn); LOADB(kn);
        }
        COMPUTE(t & 1);
        if (t + 1 < KSTEPS) {
            CVTSTORE((t + 1) & 1);
            BARRIER_LDS();
        }
    }

    // ---- epilogue: C/D layout col=lane&15, row=(lane>>4)*4+r ----
#pragma unroll
    for (int mi = 0; mi < 8; ++mi) {
        const int rbase = wr * 128 + mi * 16 + lg * 4;
#pragma unroll
        for (int r = 0; r < 4; ++r) {
            const int rr = rbase + r;
            if (rr < rows) {
#pragma unroll
                for (int ni = 0; ni < 4; ++ni) {
                    out[(size_t)(m0 + rr) * K_DIM + n0 + wc * 64 + ni * 16 + lr] =
                        acc[mi][ni][r] + bias_v[ni];
                }
            }
        }
    }
}

extern "C" void kernel_launch(void* const* d_in, const int* in_sizes, int n_in,
                              void* d_out, int out_size, void* d_ws, size_t ws_size,
                              hipStream_t stream) {
    const int*   offsets = (const int*)d_in[1];
    const int*   index   = (const int*)d_in[2];
    const float* jagged  = (const float*)d_in[3];
    const float* weight  = (const float*)d_in[4];
    const float* bias    = (const float*)d_in[5];
    float*       out     = (float*)d_out;

    dim3 grid(NWG);
    dim3 block(512);
    hipLaunchKernelGGL(jbmm_kernel, grid, block, 0, stream,
                       offsets, index, jagged, weight, bias, out);
}

// Round 14
// 83.717 us; speedup vs baseline: 1.4411x; 1.4082x over previous
//
#include <hip/hip_runtime.h>
#include <hip/hip_bf16.h>

// Problem constants
#define D_DIM 512
#define K_DIM 512
#define B_C   64

// 8-phase-template port: 256x128 tile (AI=43), 8 waves (4 wave-rows x 2 wave-cols),
// BK=64, 4 phases/K-step, chunked staging (acc 64/wave, staging <=48 live).
#define BM 256
#define BN 128
#define BK 64
#define KSTEPS 8             // D_DIM / BK
#define ROWT 4               // LMAX / BM
#define COLT 4               // K_DIM / BN
#define NWG  (B_C * ROWT * COLT)   // 1024, divisible by 8 XCDs

typedef __attribute__((ext_vector_type(8))) short bf16x8;
typedef __attribute__((ext_vector_type(4))) short bf16x4;
typedef __attribute__((ext_vector_type(4))) float f32x4;

__device__ __forceinline__ short f2bf(float f) {
    union { __hip_bfloat16 h; short s; } u;
    u.h = __float2bfloat16(f);
    return u.s;
}

// Validated zero-conflict swizzle family for 128B rows (8 x 16B slots):
// slot' = slot ^ ((r&7) ^ ((r>>2)&7))
__device__ __forceinline__ int fS(int r) { return (r & 7) ^ ((r >> 2) & 7); }

__global__ __launch_bounds__(512, 1) void jbmm_kernel(
    const int* __restrict__ offsets,   // B+1
    const int* __restrict__ index,     // B
    const float* __restrict__ jagged,  // T x D
    const float* __restrict__ weight,  // NW x D x K
    const float* __restrict__ bias,    // NW x K
    float* __restrict__ out)           // T x K
{
    __shared__ short As[2][BM * BK];   // 32 KB each
    __shared__ short Bs[2][BN * BK];   // 16 KB each  (total 96 KB)

    // XCD chunk swizzle (1024 % 8 == 0 -> bijective)
    const int bidRaw = blockIdx.x;
    const int bid = (bidRaw & 7) * (NWG / 8) + (bidRaw >> 3);

    const int b   = bid / (ROWT * COLT);
    const int rt  = (bid / COLT) % ROWT;
    const int ct  = bid % COLT;

    const int start = offsets[b];
    const int end   = offsets[b + 1];
    const int m0    = start + rt * BM;
    if (m0 >= end) return;
    const int rows = (end - m0) < BM ? (end - m0) : BM;

    const int idxw = index[b];
    const float* W = weight + (size_t)idxw * D_DIM * K_DIM;
    const int n0 = ct * BN;

    const int tid  = threadIdx.x;
    const int lane = tid & 63;
    const int wid  = tid >> 6;   // 0..7
    const int wr   = wid >> 1;   // 0..3: rows wr*64..+63
    const int wc   = wid & 1;    // 0..1: cols wc*64..+63
    const int lr   = lane & 15;
    const int lg   = lane >> 4;

    // staging maps (512 threads)
    const int arow  = tid >> 1;  // 0..255: A row
    const int ahalf = tid & 1;   // 0..1: 32 consecutive f32
    const int nq    = tid & 31;  // 0..31: B n-quad (rows 4*nq..+3)
    const int kq    = tid >> 5;  // 0..15: B k-quad (k rows kq*4..+3)

    float bias_v[4];
#pragma unroll
    for (int ni = 0; ni < 4; ++ni)
        bias_v[ni] = bias[(size_t)idxw * K_DIM + n0 + wc * 64 + ni * 16 + lr];

    f32x4 acc[4][4];             // 64 VGPR per wave
#pragma unroll
    for (int mi = 0; mi < 4; ++mi)
#pragma unroll
        for (int ni = 0; ni < 4; ++ni)
            acc[mi][ni] = (f32x4){0.f, 0.f, 0.f, 0.f};

    f32x4 aL[8];                 // A chunk in flight (32 VGPR)
    f32x4 bL[4];                 // B chunk in flight (16 VGPR)
    bf16x8 bfr[4];               // persistent B frags for current kh

#define ISSUE_A(k0_)                                                        \
    {                                                                       \
        if (arow < rows) {                                                  \
            const float* p = &jagged[(size_t)(m0 + arow) * D_DIM + (k0_) + ahalf * 32]; \
            _Pragma("unroll")                                               \
            for (int j = 0; j < 8; ++j)                                     \
                aL[j] = *reinterpret_cast<const f32x4*>(p + 4 * j);         \
        } else {                                                            \
            _Pragma("unroll")                                               \
            for (int j = 0; j < 8; ++j)                                     \
                aL[j] = (f32x4){0.f, 0.f, 0.f, 0.f};                        \
        }                                                                   \
    }

#define ISSUE_B(k0_)                                                        \
    {                                                                       \
        _Pragma("unroll")                                                   \
        for (int j = 0; j < 4; ++j)                                         \
            bL[j] = *reinterpret_cast<const f32x4*>(                        \
                &W[(size_t)((k0_) + kq * 4 + j) * K_DIM + n0 + nq * 4]);    \
    }

#define WRITE_A(c_)                                                         \
    {                                                                       \
        _Pragma("unroll")                                                   \
        for (int q = 0; q < 4; ++q) {                                       \
            bf16x8 w8;                                                      \
            w8[0] = f2bf(aL[2*q][0]);   w8[1] = f2bf(aL[2*q][1]);           \
            w8[2] = f2bf(aL[2*q][2]);   w8[3] = f2bf(aL[2*q][3]);           \
            w8[4] = f2bf(aL[2*q+1][0]); w8[5] = f2bf(aL[2*q+1][1]);         \
            w8[6] = f2bf(aL[2*q+1][2]); w8[7] = f2bf(aL[2*q+1][3]);         \
            const int sl = (ahalf * 4 + q) ^ fS(arow);                      \
            *reinterpret_cast<bf16x8*>(                                     \
                (char*)&As[c_][0] + arow * 128 + (sl << 4)) = w8;           \
        }                                                                   \
    }

#define WRITE_B(c_)                                                         \
    {                                                                       \
        _Pragma("unroll")                                                   \
        for (int np = 0; np < 4; ++np) {                                    \
            const int row = nq * 4 + np;                                    \
            bf16x4 w4;                                                      \
            w4[0] = f2bf(bL[0][np]); w4[1] = f2bf(bL[1][np]);               \
            w4[2] = f2bf(bL[2][np]); w4[3] = f2bf(bL[3][np]);               \
            *reinterpret_cast<bf16x4*>(                                     \
                (char*)&Bs[c_][0] + row * 128 +                             \
                ((((kq >> 1) ^ fS(row))) << 4) + (kq & 1) * 8) = w4;        \
        }                                                                   \
    }

#define READ_BFR(c_, kh_)                                                   \
    {                                                                       \
        _Pragma("unroll")                                                   \
        for (int ni = 0; ni < 4; ++ni) {                                    \
            const int row = wc * 64 + ni * 16 + lr;                         \
            bfr[ni] = *reinterpret_cast<bf16x8*>(                           \
                (char*)&Bs[c_][0] + row * 128 + ((((kh_) * 4 + lg) ^ fS(row)) << 4)); \
        }                                                                   \
    }

// phase core: af reads for mi-pair mp_, barrier, lgkm fence, 8 MFMA, barrier
#define PHASE_MFMA(c_, kh_, mp_)                                            \
    {                                                                       \
        bf16x8 af0, af1;                                                    \
        {                                                                   \
            const int r0 = wr * 64 + ((mp_) * 2 + 0) * 16 + lr;             \
            const int r1 = wr * 64 + ((mp_) * 2 + 1) * 16 + lr;             \
            af0 = *reinterpret_cast<bf16x8*>(                               \
                (char*)&As[c_][0] + r0 * 128 + ((((kh_) * 4 + lg) ^ fS(r0)) << 4)); \
            af1 = *reinterpret_cast<bf16x8*>(                               \
                (char*)&As[c_][0] + r1 * 128 + ((((kh_) * 4 + lg) ^ fS(r1)) << 4)); \
        }                                                                   \
        asm volatile("" ::: "memory");                                      \
        __builtin_amdgcn_s_barrier();                                       \
        asm volatile("s_waitcnt lgkmcnt(0)" ::: "memory");                  \
        __builtin_amdgcn_sched_barrier(0);                                  \
        __builtin_amdgcn_s_setprio(1);                                      \
        _Pragma("unroll")                                                   \
        for (int ni = 0; ni < 4; ++ni) {                                    \
            acc[(mp_)*2+0][ni] = __builtin_amdgcn_mfma_f32_16x16x32_bf16(   \
                af0, bfr[ni], acc[(mp_)*2+0][ni], 0, 0, 0);                 \
            acc[(mp_)*2+1][ni] = __builtin_amdgcn_mfma_f32_16x16x32_bf16(   \
                af1, bfr[ni], acc[(mp_)*2+1][ni], 0, 0, 0);                 \
        }                                                                   \
        __builtin_amdgcn_s_setprio(0);                                      \
        asm volatile("" ::: "memory");                                      \
        __builtin_amdgcn_s_barrier();                                       \
        asm volatile("" ::: "memory");                                      \
    }

    // ---- prologue: stage tile 0 (bulk; compiler inserts precise waits) ----
    ISSUE_A(0); ISSUE_B(0);
    WRITE_A(0); WRITE_B(0);
    asm volatile("s_waitcnt lgkmcnt(0)" ::: "memory");
    __builtin_amdgcn_s_barrier();
    asm volatile("" ::: "memory");

    // ---- main loop: 4 phases per K-step ----
    for (int t = 0; t < KSTEPS; ++t) {
        const int cur = t & 1;
        const int nxt = cur ^ 1;
        const bool more = (t + 1 < KSTEPS);
        const int kn = (t + 1) * BK;

        // phase 0: issue A chunk of next tile; bfr(kh0); MFMA kh0 mi{0,1}
        if (more) ISSUE_A(kn);
        READ_BFR(cur, 0);
        PHASE_MFMA(cur, 0, 0);

        // phase 1: issue B chunk; MFMA kh0 mi{2,3}
        if (more) ISSUE_B(kn);
        PHASE_MFMA(cur, 0, 1);

        // phase 2: consume A chunk (counted vmcnt: 4 B loads newer); bfr(kh1); MFMA kh1 mi{0,1}
        if (more) {
            asm volatile("s_waitcnt vmcnt(4)" ::: "memory");
            WRITE_A(nxt);
        }
        READ_BFR(cur, 1);
        PHASE_MFMA(cur, 1, 0);

        // phase 3: consume B chunk; MFMA kh1 mi{2,3}
        if (more) {
            asm volatile("s_waitcnt vmcnt(0)" ::: "memory");
            WRITE_B(nxt);
        }
        PHASE_MFMA(cur, 1, 1);
    }

    // ---- epilogue: C/D layout col=lane&15, row=(lane>>4)*4+r ----
#pragma unroll
    for (int mi = 0; mi < 4; ++mi) {
        const int rbase = wr * 64 + mi * 16 + lg * 4;
#pragma unroll
        for (int r = 0; r < 4; ++r) {
            const int rr = rbase + r;
            if (rr < rows) {
#pragma unroll
                for (int ni = 0; ni < 4; ++ni) {
                    out[(size_t)(m0 + rr) * K_DIM + n0 + wc * 64 + ni * 16 + lr] =
                        acc[mi][ni][r] + bias_v[ni];
                }
            }
        }
    }
}

extern "C" void kernel_launch(void* const* d_in, const int* in_sizes, int n_in,
                              void* d_out, int out_size, void* d_ws, size_t ws_size,
                              hipStream_t stream) {
    const int*   offsets = (const int*)d_in[1];
    const int*   index   = (const int*)d_in[2];
    const float* jagged  = (const float*)d_in[3];
    const float* weight  = (const float*)d_in[4];
    const float* bias    = (const float*)d_in[5];
    float*       out     = (float*)d_out;

    dim3 grid(NWG);
    dim3 block(512);
    hipLaunchKernelGGL(jbmm_kernel, grid, block, 0, stream,
                       offsets, index, jagged, weight, bias, out);
}